// Round 1
// baseline (1957.519 us; speedup 1.0000x reference)
//
#include <hip/hip_runtime.h>

// ---------------- constants ----------------
#define BTOT   4096
#define DATA   16
#define HID    64
#define VFW    128
#define LAB    10
#define TPTS   201
#define NSEG   200
#define NSTEPS 100
#define MT     16            // batch rows per block
#define NBLK   (BTOT / MT)   // 256

typedef __attribute__((ext_vector_type(8))) short short8;   // 8 bf16 = 4 VGPRs
typedef __attribute__((ext_vector_type(4))) float f32x4;

__device__ __forceinline__ short f2bf(float f) {
    unsigned u = __builtin_bit_cast(unsigned, f);
    u = (u + 0x7FFFu + ((u >> 16) & 1u)) >> 16;   // RNE
    return (short)u;
}

__device__ __forceinline__ float tanh_fast(float x) {
    // tanh(x) = 1 - 2/(exp(2x)+1); saturates correctly at +-inf
    float e = __expf(2.0f * x);
    return 1.0f - 2.0f * __builtin_amdgcn_rcpf(e + 1.0f);
}

// ---------------- weight fragment packing ----------------
// For GEMM h = A(16xK) * B(KxN) with B = W^T (W is (N,K) row-major):
// frag slot index = (nt*KS + ks)*64 + lane ; each slot = 8 bf16 (16B)
// holding W[16*nt + (lane&15)][32*ks + 8*(lane>>4) + j], j=0..7
__global__ void pack_w(const float* __restrict__ W, short* __restrict__ outp,
                       int N, int K) {
    int tid = blockIdx.x * blockDim.x + threadIdx.x;
    int KS = K >> 5;
    int total = (N >> 4) * KS * 64;
    if (tid >= total) return;
    int ln = tid & 63;
    int fs = tid >> 6;
    int ks = fs % KS;
    int nt = fs / KS;
    int n  = nt * 16 + (ln & 15);
    int k0 = ks * 32 + (ln >> 4) * 8;
    const float* src = W + n * K + k0;
    short8 v;
#pragma unroll
    for (int j = 0; j < 8; ++j) v[j] = f2bf(src[j]);
    *(((short8*)outp) + tid) = v;
}

// ---------------- persistent CDE kernel ----------------
__global__ __launch_bounds__(256) void cde_main(
    const float* __restrict__ ts_g,  const float* __restrict__ coeffs,
    const float* __restrict__ x0,    const float* __restrict__ lin1_w,
    const float* __restrict__ lin1_b,const float* __restrict__ w0g,
    const float* __restrict__ b0g,   const float* __restrict__ b1g,
    const float* __restrict__ b2g,   const float* __restrict__ l2w,
    const float* __restrict__ l2b,
    const short8* __restrict__ w1p,  const short8* __restrict__ w2p,
    float* __restrict__ out)
{
    __shared__ float ts_sh[TPTS];
    __shared__ float y32[MT * HID];
    __shared__ float k1b[MT * HID];
    __shared__ float k2b[MT * HID];
    __shared__ __align__(16) short ybf[MT * 72];     // 16x64 bf16, stride 72
    __shared__ __align__(16) short h1bf[MT * 136];   // 16x128 bf16, stride 136
    __shared__ __align__(16) short h2bf[MT * 136];
    __shared__ float b0s[VFW], b1s[VFW], b2s[HID * DATA];
    __shared__ __align__(16) short w0f[8 * 2 * 64 * 8];  // w0 frags in LDS (16KB)
    __shared__ float lgts[MT * 12];

    const int tid  = threadIdx.x;
    const int lane = tid & 63;
    const int wave = tid >> 6;       // 0..3
    const int lm   = lane & 15;      // row (A) / col (B,D) id
    const int lg   = lane >> 4;      // k-group / row-group
    const int row0 = blockIdx.x * MT;

    // ---- one-time init ----
    for (int i = tid; i < TPTS; i += 256) ts_sh[i] = ts_g[i];
    for (int i = tid; i < VFW;  i += 256) { b0s[i] = b0g[i]; b1s[i] = b1g[i]; }
    for (int i = tid; i < HID * DATA; i += 256) b2s[i] = b2g[i];
    // pack w0 (N=128,K=64) into LDS fragment order
    for (int f = tid; f < 8 * 2 * 64; f += 256) {
        int ln = f & 63, fs = f >> 6;
        int nt = fs >> 1, ks = fs & 1;
        int n  = nt * 16 + (ln & 15);
        int k0 = ks * 32 + (ln >> 4) * 8;
        const float* src = w0g + n * HID + k0;
#pragma unroll
        for (int j = 0; j < 8; ++j) w0f[f * 8 + j] = f2bf(src[j]);
    }
    // y0 = x0 @ lin1_w^T + lin1_b   (fp32 scalar, tiny)
    for (int idx = tid; idx < MT * HID; idx += 256) {
        int m = idx >> 6, h = idx & 63;
        float s = lin1_b[h];
        const float* xr = x0 + (row0 + m) * DATA;
        const float* wr = lin1_w + h * DATA;
#pragma unroll
        for (int k = 0; k < DATA; ++k) s += xr[k] * wr[k];
        y32[idx] = s;
        ybf[m * 72 + h] = f2bf(s);
    }
    __syncthreads();

    float t = ts_sh[0];
    const float dtv = (ts_sh[TPTS - 1] - ts_sh[0]) / 100.0f;  // matches (t1-t0)/N_STEPS
    const float half_dt = 0.5f * dtv;

    auto evalVF = [&](float tcur, float* kdst) {
        // ---- GEMM1: h1 = relu(ybf(16x64) @ w0^T + b0) ----
        short8 a0 = *(const short8*)&ybf[lm * 72 + 0  + lg * 8];
        short8 a1 = *(const short8*)&ybf[lm * 72 + 32 + lg * 8];
#pragma unroll
        for (int i = 0; i < 2; ++i) {
            int nt = wave * 2 + i;
            short8 bb0 = *(const short8*)&w0f[((nt * 2 + 0) * 64 + lane) * 8];
            short8 bb1 = *(const short8*)&w0f[((nt * 2 + 1) * 64 + lane) * 8];
            f32x4 acc = {0.f, 0.f, 0.f, 0.f};
            acc = __builtin_amdgcn_mfma_f32_16x16x32_bf16(a0, bb0, acc, 0, 0, 0);
            acc = __builtin_amdgcn_mfma_f32_16x16x32_bf16(a1, bb1, acc, 0, 0, 0);
            int n = nt * 16 + lm;
            float bias = b0s[n];
#pragma unroll
            for (int r = 0; r < 4; ++r) {
                float v = fmaxf(acc[r] + bias, 0.f);
                h1bf[(4 * lg + r) * 136 + n] = f2bf(v);
            }
        }
        __syncthreads();
        // ---- GEMM2: h2 = relu(h1(16x128) @ w1^T + b1) ----
        short8 a[4];
#pragma unroll
        for (int ks = 0; ks < 4; ++ks)
            a[ks] = *(const short8*)&h1bf[lm * 136 + ks * 32 + lg * 8];
#pragma unroll
        for (int i = 0; i < 2; ++i) {
            int nt = wave * 2 + i;
            f32x4 acc = {0.f, 0.f, 0.f, 0.f};
#pragma unroll
            for (int ks = 0; ks < 4; ++ks)
                acc = __builtin_amdgcn_mfma_f32_16x16x32_bf16(a[ks], w1p[(nt * 4 + ks) * 64 + lane], acc, 0, 0, 0);
            int n = nt * 16 + lm;
            float bias = b1s[n];
#pragma unroll
            for (int r = 0; r < 4; ++r) {
                float v = fmaxf(acc[r] + bias, 0.f);
                h2bf[(4 * lg + r) * 136 + n] = f2bf(v);
            }
        }
        __syncthreads();
        // ---- control deriv cd[lm] (exact searchsorted-left via windowed scan) ----
        int g  = (int)(tcur * 200.0f);
        int i0 = g - 2; i0 = i0 < 0 ? 0 : (i0 > 196 ? 196 : i0);
        float v0 = ts_sh[i0 + 1], v1 = ts_sh[i0 + 2], v2 = ts_sh[i0 + 3], v3 = ts_sh[i0 + 4];
        int aidx = i0 + (v0 < tcur) + (v1 < tcur) + (v2 < tcur) + (v3 < tcur);
        aidx = aidx > (NSEG - 1) ? (NSEG - 1) : aidx;
        float dtl = tcur - ts_sh[aidx];
        const float* cc = coeffs + (aidx * DATA + lm) * 4;
        float cd_l = cc[0] + dtl * (cc[1] + dtl * (cc[2] + dtl * cc[3]));
        // ---- GEMM3 + tanh + contraction: kdst = einsum(tanh(h2@w2^T+b2), cd) ----
        short8 A2[4];
#pragma unroll
        for (int ks = 0; ks < 4; ++ks)
            A2[ks] = *(const short8*)&h2bf[lm * 136 + ks * 32 + lg * 8];
#pragma unroll 4
        for (int i = 0; i < 16; ++i) {
            int nt = wave * 16 + i;          // nt == output column h
            f32x4 acc = {0.f, 0.f, 0.f, 0.f};
#pragma unroll
            for (int ks = 0; ks < 4; ++ks)
                acc = __builtin_amdgcn_mfma_f32_16x16x32_bf16(A2[ks], w2p[(nt * 4 + ks) * 64 + lane], acc, 0, 0, 0);
            int n = nt * 16 + lm;            // n%16 == d == lm
            float bz = b2s[n];
            float p0 = tanh_fast(acc[0] + bz) * cd_l;
            float p1 = tanh_fast(acc[1] + bz) * cd_l;
            float p2 = tanh_fast(acc[2] + bz) * cd_l;
            float p3 = tanh_fast(acc[3] + bz) * cd_l;
#pragma unroll
            for (int mk = 8; mk >= 1; mk >>= 1) {
                p0 += __shfl_xor(p0, mk);
                p1 += __shfl_xor(p1, mk);
                p2 += __shfl_xor(p2, mk);
                p3 += __shfl_xor(p3, mk);
            }
            if (lm < 4) {
                float v = (lm == 0) ? p0 : (lm == 1) ? p1 : (lm == 2) ? p2 : p3;
                kdst[(4 * lg + lm) * HID + nt] = v;
            }
        }
        __syncthreads();
    };

    // ---- Heun time loop ----
    for (int s = 0; s < NSTEPS; ++s) {
        evalVF(t, k1b);
        for (int idx = tid; idx < MT * HID; idx += 256) {
            int m = idx >> 6, h = idx & 63;
            float yt = y32[idx] + dtv * k1b[idx];
            ybf[m * 72 + h] = f2bf(yt);
        }
        __syncthreads();
        float tn = t + dtv;
        evalVF(tn, k2b);
        for (int idx = tid; idx < MT * HID; idx += 256) {
            int m = idx >> 6, h = idx & 63;
            float yn = y32[idx] + half_dt * (k1b[idx] + k2b[idx]);
            y32[idx] = yn;
            ybf[m * 72 + h] = f2bf(yn);
        }
        __syncthreads();
        t = tn;
    }

    // ---- logits + softmax (fp32 scalar) ----
    if (tid < MT * LAB) {
        int m = tid / LAB, j = tid % LAB;
        float s = l2b[j];
        const float* wr = l2w + j * HID;
#pragma unroll
        for (int h = 0; h < HID; ++h) s += y32[m * HID + h] * wr[h];
        lgts[m * 12 + j] = s;
    }
    __syncthreads();
    if (tid < MT) {
        int m = tid;
        float mx = lgts[m * 12];
#pragma unroll
        for (int j = 1; j < LAB; ++j) mx = fmaxf(mx, lgts[m * 12 + j]);
        float e[LAB]; float sum = 0.f;
#pragma unroll
        for (int j = 0; j < LAB; ++j) { e[j] = __expf(lgts[m * 12 + j] - mx); sum += e[j]; }
#pragma unroll
        for (int j = 0; j < LAB; ++j) out[(row0 + m) * LAB + j] = e[j] / sum;
    }
}

extern "C" void kernel_launch(void* const* d_in, const int* in_sizes, int n_in,
                              void* d_out, int out_size, void* d_ws, size_t ws_size,
                              hipStream_t stream) {
    (void)in_sizes; (void)n_in; (void)out_size; (void)ws_size;
    const float* ts     = (const float*)d_in[0];
    const float* coeffs = (const float*)d_in[1];
    const float* x0     = (const float*)d_in[2];
    const float* lin1_w = (const float*)d_in[3];
    const float* lin1_b = (const float*)d_in[4];
    const float* w0     = (const float*)d_in[5];
    const float* b0     = (const float*)d_in[6];
    const float* w1     = (const float*)d_in[7];
    const float* b1     = (const float*)d_in[8];
    const float* w2     = (const float*)d_in[9];
    const float* b2     = (const float*)d_in[10];
    const float* l2w    = (const float*)d_in[11];
    const float* l2b    = (const float*)d_in[12];

    short* w1pack = (short*)d_ws;                          // 8*4*64 frags = 32KB
    short* w2pack = (short*)((char*)d_ws + 2048 * 16);     // 64*4*64 frags = 256KB

    pack_w<<<dim3(8),  256, 0, stream>>>(w1, w1pack, 128, 128);
    pack_w<<<dim3(64), 256, 0, stream>>>(w2, w2pack, 1024, 128);
    cde_main<<<dim3(NBLK), 256, 0, stream>>>(ts, coeffs, x0, lin1_w, lin1_b,
        w0, b0, b1, b2, l2w, l2b,
        (const short8*)w1pack, (const short8*)w2pack, (float*)d_out);
}

// Round 2
// 521.519 us; speedup vs baseline: 3.7535x; 3.7535x over previous
//
#include <hip/hip_runtime.h>

// ---------------- constants ----------------
#define BTOT   4096
#define DATA   16
#define HID    64
#define VFW    128
#define LAB    10
#define TPTS   201
#define NSEG   200
#define NSTEPS 100
#define MT     16            // batch rows per block
#define NBLK   (BTOT / MT)   // 256
#define YS     68            // padded fp32 stride for y32 (68 % 32 == 4 -> 2-way, free)

typedef __attribute__((ext_vector_type(8))) short short8;   // 8 bf16 = 4 VGPRs
typedef __attribute__((ext_vector_type(4))) float f32x4;

__device__ __forceinline__ short f2bf(float f) {
    unsigned u = __builtin_bit_cast(unsigned, f);
    u = (u + 0x7FFFu + ((u >> 16) & 1u)) >> 16;   // RNE
    return (short)u;
}

__device__ __forceinline__ float tanh_fast(float x) {
    float e = __expf(2.0f * x);
    return 1.0f - 2.0f * __builtin_amdgcn_rcpf(e + 1.0f);
}

// ---------------- weight fragment packing ----------------
// slot index = (nt*KS + ks)*64 + lane ; each slot = 8 bf16 (16B)
// holding W[16*nt + (lane&15)][32*ks + 8*(lane>>4) + j], j=0..7
// This layout serves as B-fragment (col=lane&15) AND as A-fragment (row=lane&15).
__global__ void pack_w(const float* __restrict__ W, short* __restrict__ outp,
                       int N, int K) {
    int tid = blockIdx.x * blockDim.x + threadIdx.x;
    int KS = K >> 5;
    int total = (N >> 4) * KS * 64;
    if (tid >= total) return;
    int ln = tid & 63;
    int fs = tid >> 6;
    int ks = fs % KS;
    int nt = fs / KS;
    int n  = nt * 16 + (ln & 15);
    int k0 = ks * 32 + (ln >> 4) * 8;
    const float* src = W + n * K + k0;
    short8 v;
#pragma unroll
    for (int j = 0; j < 8; ++j) v[j] = f2bf(src[j]);
    *(((short8*)outp) + tid) = v;
}

// ---------------- persistent CDE kernel ----------------
__global__ __launch_bounds__(512, 2) void cde_main(
    const float* __restrict__ ts_g,  const float* __restrict__ coeffs,
    const float* __restrict__ x0,    const float* __restrict__ lin1_w,
    const float* __restrict__ lin1_b,
    const float* __restrict__ b0g,   const float* __restrict__ b1g,
    const float* __restrict__ b2g,   const float* __restrict__ l2w,
    const float* __restrict__ l2b,
    const short8* __restrict__ w0p,  const short8* __restrict__ w1p,
    const short8* __restrict__ w2p,  float* __restrict__ out)
{
    __shared__ float ts_sh[TPTS];
    __shared__ float y32[MT * YS];
    __shared__ __align__(16) short ybf[MT * 72];     // 16x64 bf16, stride 72
    __shared__ __align__(16) short h1bf[MT * 136];   // 16x128 bf16, stride 136
    __shared__ __align__(16) short h2bf[MT * 136];
    __shared__ float b2s[HID * DATA];
    __shared__ float lgts[MT * 12];

    const int tid  = threadIdx.x;
    const int lane = tid & 63;
    const int wave = tid >> 6;       // 0..7
    const int lm   = lane & 15;
    const int lg   = lane >> 4;      // 0..3
    const int row0 = blockIdx.x * MT;

    // ---- one-time init ----
    for (int i = tid; i < TPTS; i += 512) ts_sh[i] = ts_g[i];
    for (int i = tid; i < HID * DATA; i += 512) b2s[i] = b2g[i];
    for (int idx = tid; idx < MT * HID; idx += 512) {
        int m = idx >> 6, h = idx & 63;
        float s = lin1_b[h];
        const float* xr = x0 + (row0 + m) * DATA;
        const float* wr = lin1_w + h * DATA;
#pragma unroll
        for (int k = 0; k < DATA; ++k) s += xr[k] * wr[k];
        y32[m * YS + h] = s;
        ybf[m * 72 + h] = f2bf(s);
    }
    // ---- weights -> registers (persistent) ----
    short8 w0r0 = w0p[(wave * 2 + 0) * 64 + lane];
    short8 w0r1 = w0p[(wave * 2 + 1) * 64 + lane];
    short8 w1r[4];
#pragma unroll
    for (int ks = 0; ks < 4; ++ks) w1r[ks] = w1p[(wave * 4 + ks) * 64 + lane];
    short8 w2r[8][4];
#pragma unroll
    for (int i = 0; i < 8; ++i)
#pragma unroll
        for (int ks = 0; ks < 4; ++ks)
            w2r[i][ks] = w2p[((wave * 8 + i) * 4 + ks) * 64 + lane];
    const float b0v = b0g[wave * 16 + lm];
    const float b1v = b1g[wave * 16 + lm];
    __syncthreads();

    float t = ts_sh[0];
    const float dtv = (ts_sh[TPTS - 1] - ts_sh[0]) / 100.0f;
    const float half_dt = 0.5f * dtv;

    // evalVF: computes k[m=lm][h=wave*8+i] into sacc[i] (all lanes hold it)
    auto evalVF = [&](float tcur, float (&sacc)[8]) {
        // ---- GEMM1: h1 = relu(y(16x64) @ w0^T + b0); this wave: nt = wave ----
        short8 a0 = *(const short8*)&ybf[lm * 72 + 0  + lg * 8];
        short8 a1 = *(const short8*)&ybf[lm * 72 + 32 + lg * 8];
        f32x4 acc1 = {0.f, 0.f, 0.f, 0.f};
        acc1 = __builtin_amdgcn_mfma_f32_16x16x32_bf16(a0, w0r0, acc1, 0, 0, 0);
        acc1 = __builtin_amdgcn_mfma_f32_16x16x32_bf16(a1, w0r1, acc1, 0, 0, 0);
        {
            int n = wave * 16 + lm;
#pragma unroll
            for (int r = 0; r < 4; ++r)
                h1bf[(4 * lg + r) * 136 + n] = f2bf(fmaxf(acc1[r] + b0v, 0.f));
        }
        __syncthreads();
        // ---- GEMM2: h2 = relu(h1(16x128) @ w1^T + b1); nt = wave ----
        short8 a[4];
#pragma unroll
        for (int ks = 0; ks < 4; ++ks)
            a[ks] = *(const short8*)&h1bf[lm * 136 + ks * 32 + lg * 8];
        f32x4 acc2 = {0.f, 0.f, 0.f, 0.f};
#pragma unroll
        for (int ks = 0; ks < 4; ++ks)
            acc2 = __builtin_amdgcn_mfma_f32_16x16x32_bf16(a[ks], w1r[ks], acc2, 0, 0, 0);
        {
            int n = wave * 16 + lm;
#pragma unroll
            for (int r = 0; r < 4; ++r)
                h2bf[(4 * lg + r) * 136 + n] = f2bf(fmaxf(acc2[r] + b1v, 0.f));
        }
        // ---- control deriv for d = 4*lg + r (overlaps with barrier wait) ----
        float cdr[4];
        {
            int g  = (int)(tcur * 200.0f);
            int i0 = g - 2; i0 = i0 < 0 ? 0 : (i0 > 196 ? 196 : i0);
            float v0 = ts_sh[i0 + 1], v1 = ts_sh[i0 + 2], v2 = ts_sh[i0 + 3], v3 = ts_sh[i0 + 4];
            int aidx = i0 + (v0 < tcur) + (v1 < tcur) + (v2 < tcur) + (v3 < tcur);
            aidx = aidx > (NSEG - 1) ? (NSEG - 1) : aidx;
            float dtl = tcur - ts_sh[aidx];
#pragma unroll
            for (int r = 0; r < 4; ++r) {
                const f32x4 cc = *(const f32x4*)(coeffs + (aidx * DATA + 4 * lg + r) * 4);
                cdr[r] = cc[0] + dtl * (cc[1] + dtl * (cc[2] + dtl * cc[3]));
            }
        }
        __syncthreads();
        // ---- GEMM3 (swapped operands): D[n][m] = W2'(16x128) x h2^T ----
        short8 hb[4];
#pragma unroll
        for (int ks = 0; ks < 4; ++ks)
            hb[ks] = *(const short8*)&h2bf[lm * 136 + ks * 32 + lg * 8];
#pragma unroll
        for (int i = 0; i < 8; ++i) {
            f32x4 acc = {0.f, 0.f, 0.f, 0.f};
#pragma unroll
            for (int ks = 0; ks < 4; ++ks)
                acc = __builtin_amdgcn_mfma_f32_16x16x32_bf16(w2r[i][ks], hb[ks], acc, 0, 0, 0);
            int nb = (wave * 8 + i) * 16 + 4 * lg;       // n = h*16 + d, d = 4lg+r
            const f32x4 bz = *(const f32x4*)&b2s[nb];
            float sv = tanh_fast(acc[0] + bz[0]) * cdr[0]
                     + tanh_fast(acc[1] + bz[1]) * cdr[1]
                     + tanh_fast(acc[2] + bz[2]) * cdr[2]
                     + tanh_fast(acc[3] + bz[3]) * cdr[3];
            sv += __shfl_xor(sv, 16);
            sv += __shfl_xor(sv, 32);
            sacc[i] = sv;                                 // k[m=lm][h=wave*8+i]
        }
    };

    // ---- Heun time loop (k1/k2 stay in registers) ----
    for (int s = 0; s < NSTEPS; ++s) {
        float k1v[8], k2v[8];
        evalVF(t, k1v);
        if (lg == 0) {                                    // ybf = bf16(y + dt*k1)
            short8 yb;
#pragma unroll
            for (int i = 0; i < 8; ++i)
                yb[i] = f2bf(y32[lm * YS + wave * 8 + i] + dtv * k1v[i]);
            *(short8*)&ybf[lm * 72 + wave * 8] = yb;
        }
        __syncthreads();
        float tn = t + dtv;
        evalVF(tn, k2v);
        if (lg == 0) {                                    // y += dt/2 (k1+k2)
            short8 yb;
#pragma unroll
            for (int i = 0; i < 8; ++i) {
                float yn = y32[lm * YS + wave * 8 + i] + half_dt * (k1v[i] + k2v[i]);
                y32[lm * YS + wave * 8 + i] = yn;
                yb[i] = f2bf(yn);
            }
            *(short8*)&ybf[lm * 72 + wave * 8] = yb;
        }
        __syncthreads();
        t = tn;
    }

    // ---- logits + softmax (fp32 scalar) ----
    if (tid < MT * LAB) {
        int m = tid / LAB, j = tid % LAB;
        float s = l2b[j];
        const float* wr = l2w + j * HID;
#pragma unroll
        for (int h = 0; h < HID; ++h) s += y32[m * YS + h] * wr[h];
        lgts[m * 12 + j] = s;
    }
    __syncthreads();
    if (tid < MT) {
        int m = tid;
        float mx = lgts[m * 12];
#pragma unroll
        for (int j = 1; j < LAB; ++j) mx = fmaxf(mx, lgts[m * 12 + j]);
        float e[LAB]; float sum = 0.f;
#pragma unroll
        for (int j = 0; j < LAB; ++j) { e[j] = __expf(lgts[m * 12 + j] - mx); sum += e[j]; }
#pragma unroll
        for (int j = 0; j < LAB; ++j) out[(row0 + m) * LAB + j] = e[j] / sum;
    }
}

extern "C" void kernel_launch(void* const* d_in, const int* in_sizes, int n_in,
                              void* d_out, int out_size, void* d_ws, size_t ws_size,
                              hipStream_t stream) {
    (void)in_sizes; (void)n_in; (void)out_size; (void)ws_size;
    const float* ts     = (const float*)d_in[0];
    const float* coeffs = (const float*)d_in[1];
    const float* x0     = (const float*)d_in[2];
    const float* lin1_w = (const float*)d_in[3];
    const float* lin1_b = (const float*)d_in[4];
    const float* w0     = (const float*)d_in[5];
    const float* b0     = (const float*)d_in[6];
    const float* w1     = (const float*)d_in[7];
    const float* b1     = (const float*)d_in[8];
    const float* w2     = (const float*)d_in[9];
    const float* b2     = (const float*)d_in[10];
    const float* l2w    = (const float*)d_in[11];
    const float* l2b    = (const float*)d_in[12];

    short* w0pack = (short*)d_ws;                           // 1024 slots = 16 KB
    short* w1pack = (short*)((char*)d_ws + 16384);          // 2048 slots = 32 KB
    short* w2pack = (short*)((char*)d_ws + 49152);          // 16384 slots = 256 KB

    pack_w<<<dim3(4),  256, 0, stream>>>(w0, w0pack, 128, 64);
    pack_w<<<dim3(8),  256, 0, stream>>>(w1, w1pack, 128, 128);
    pack_w<<<dim3(64), 256, 0, stream>>>(w2, w2pack, 1024, 128);
    cde_main<<<dim3(NBLK), 512, 0, stream>>>(ts, coeffs, x0, lin1_w, lin1_b,
        b0, b1, b2, l2w, l2b,
        (const short8*)w0pack, (const short8*)w1pack, (const short8*)w2pack,
        (float*)d_out);
}